// Round 11
// baseline (271.404 us; speedup 1.0000x reference)
//
#include <hip/hip_runtime.h>
#include <hip/hip_bf16.h>

#define NN 25000
#define NE 100000
#define FIN 32
#define DD 64
#define NG 1000

typedef unsigned short u16;
typedef __attribute__((ext_vector_type(8))) short short8;
typedef __attribute__((ext_vector_type(4))) float f32x4;

__device__ __forceinline__ float b2f(u16 u) {
    union { unsigned int i; float f; } v; v.i = ((unsigned int)u) << 16; return v.f;
}
__device__ __forceinline__ u16 f2b(float f) {
    __hip_bfloat16 h = __float2bfloat16(f);
    return __builtin_bit_cast(u16, h);
}
// edge_index may be int64 read as int32 words: odd words would all be 0.
__device__ __forceinline__ bool idx_is_i64(const int* e) {
    return (e[1] == 0) & (e[3] == 0) & (e[5] == 0) & (e[7] == 0) & (e[9] == 0);
}
__device__ __forceinline__ int ld_src(const int* e, int i, bool i64) {
    return i64 ? e[2 * i] : e[i];
}
__device__ __forceinline__ int ld_dst(const int* e, int i, bool i64) {
    return i64 ? e[2 * (NE + i)] : e[NE + i];
}

// ---- fused pre-pass: blocks [0,6250) = lin0; blocks [6250,7274) = Bt2 build + zeroing ----
// Bt2 fragment-major: idx = kc*4096 + (s*4+c)*512 + lane*8 + j  holds
// B[k = kc*64 + s*32 + (lane>>4)*8 + j][o = c*16 + (lane&15)]  (r>=4096 -> be2 rows).
__global__ __launch_bounds__(256) void k_pre(const float* __restrict__ x,
                                             const float* __restrict__ W0,
                                             const float* __restrict__ b0,
                                             u16* __restrict__ x1b,
                                             const float* __restrict__ We2,
                                             const float* __restrict__ be2,
                                             float* __restrict__ agg,
                                             float* __restrict__ pooled,
                                             u16* __restrict__ Bt2) {
    __shared__ float sW[FIN * DD];
    __shared__ float sx[4 * FIN];
    if (blockIdx.x < 6250) {
        int tid = threadIdx.x;
        for (int i = tid; i < FIN * DD; i += 256) sW[i] = W0[i];
        int nbase = blockIdx.x * 4;
        for (int i = tid; i < 4 * FIN; i += 256) {
            int nl = i >> 5, f = i & 31;
            int n = nbase + nl;
            sx[i] = (n < NN) ? x[n * FIN + f] : 0.f;
        }
        __syncthreads();
        int lane = tid & 63, nl = tid >> 6;
        int n = nbase + nl;
        if (n < NN) {
            float acc = b0[lane];
            #pragma unroll
            for (int f = 0; f < FIN; f++) acc += sx[nl * FIN + f] * sW[f * DD + lane];
            x1b[n * DD + lane] = f2b(fmaxf(acc, 0.f));
        }
    } else {
        int tid = (blockIdx.x - 6250) * 256 + threadIdx.x;
        int stride = 1024 * 256;
        for (int idx = tid; idx < 65 * 4096; idx += stride) {
            int kc = idx >> 12;
            int rem = idx & 4095;
            int f = rem >> 9;
            int ln = (rem >> 3) & 63;
            int j = idx & 7;
            int s = f >> 2, c = f & 3;
            int o = c * 16 + (ln & 15);
            int r = kc * 64 + s * 32 + (ln >> 4) * 8 + j;
            float v = (r < 4096) ? We2[(r >> 6) * 4096 + (r & 63) * 64 + o]
                                 : be2[(r - 4096) * 64 + o];
            Bt2[idx] = f2b(v);
        }
        for (int idx = tid; idx < NN * DD; idx += stride) agg[idx] = 0.f;
        for (int idx = tid; idx < NG * DD; idx += stride) pooled[idx] = 0.f;
    }
}

// ---- fused NNConv message GEMM + scatter -------------------------------------------------
// Waves split ROWS (32 each); t folded into bf16 A-repack (2 t-reads/iter). B staged in
// LDS in fragment-major layout (verbatim Bt2 copy) -> conflict-free b128 reads & writes.
// 4 kc-chunks per barrier-pair = 64 MFMAs/wave between barriers.
// LDS: sB 32768 (aliases sX 18432 used in phases 1-2) + sT 16384 + 2816 = 51968 B.
__global__ __launch_bounds__(256) void k_msg(const float* __restrict__ ea,
                                             const int* __restrict__ eidx,
                                             const float* __restrict__ We1,
                                             const float* __restrict__ be1,
                                             const u16* __restrict__ x1b,
                                             const u16* __restrict__ Bt2,
                                             float* __restrict__ agg) {
    __shared__ __align__(16) u16 sB[16384];     // 32 KB staging; sX alias (128*72 u16)
    __shared__ u16 sT[64 * 128];                // t transposed [k][e], bf16
    __shared__ float sWe1[8 * 64];
    __shared__ float sbe1[64];
    __shared__ int sDst[128];
    const int tid = threadIdx.x;
    const int lane = tid & 63, wv = tid >> 6;
    const int ll = lane & 15, quad = lane >> 4;
    const int e0 = blockIdx.x * 128;
    const bool i64 = idx_is_i64(eidx);
    u16* sX = sB;   // alias: sX is dead once fragments are hoisted (before first staging)

    for (int i = tid; i < 512; i += 256) sWe1[i] = We1[i];
    if (tid < 64) sbe1[tid] = be1[tid];
    if (tid < 128) sDst[tid] = (e0 + tid < NE) ? ld_dst(eidx, e0 + tid, i64) : 0;

    // phase 1: gather x1 rows (bf16) for 128 edges; load edge_attr to regs
    const int eg2 = e0 + (tid >> 1);
    {
        int i0 = (tid & 1) * 32;
        if (eg2 < NE) {
            int sv = ld_src(eidx, eg2, i64);
            const u16* xr = x1b + sv * 64 + i0;
            #pragma unroll
            for (int c = 0; c < 4; c++)
                *(uint4*)&sX[(tid >> 1) * 72 + i0 + c * 8] = *(const uint4*)(xr + c * 8);
        } else {
            uint4 z = make_uint4(0, 0, 0, 0);
            #pragma unroll
            for (int c = 0; c < 4; c++)
                *(uint4*)&sX[(tid >> 1) * 72 + i0 + c * 8] = z;
        }
    }
    float eav[8];
    if (eg2 < NE) {
        f32x4 v0 = *(const f32x4*)(ea + eg2 * 8);
        f32x4 v1 = *(const f32x4*)(ea + eg2 * 8 + 4);
        #pragma unroll
        for (int f = 0; f < 4; f++) { eav[f] = v0[f]; eav[4 + f] = v1[f]; }
    } else {
        #pragma unroll
        for (int f = 0; f < 8; f++) eav[f] = 0.f;
    }
    __syncthreads();

    // phase 2: t[e,k] = relu(ea @ We1 + be1) (f32 math), stored bf16 transposed [k][e]
    {
        int e = tid >> 1, k0 = (tid & 1) * 32;
        for (int kk = 0; kk < 32; kk++) {
            int k = k0 + kk;
            float acc = sbe1[k];
            #pragma unroll
            for (int f = 0; f < 8; f++) acc += eav[f] * sWe1[f * 64 + k];
            sT[k * 128 + e] = (eg2 < NE) ? f2b(fmaxf(acc, 0.f)) : (u16)0;
        }
    }
    __syncthreads();

    // hoist xs fragments: f32 (for t-scaling repack) + raw bf16 (for bias chunk)
    float xsf[2][2][8];
    short8 xab[2][2];
    #pragma unroll
    for (int rt = 0; rt < 2; rt++)
        #pragma unroll
        for (int s = 0; s < 2; s++) {
            short8 v = *(const short8*)&sX[(wv * 32 + rt * 16 + ll) * 72 + s * 32 + quad * 8];
            xab[rt][s] = v;
            #pragma unroll
            for (int j = 0; j < 8; j++) xsf[rt][s][j] = b2f((u16)v[j]);
        }

    f32x4 acc[2][4];
    #pragma unroll
    for (int rt = 0; rt < 2; rt++)
        #pragma unroll
        for (int c = 0; c < 4; c++) acc[rt][c] = (f32x4){0.f, 0.f, 0.f, 0.f};

    // K-loop: 17 groups (16 x 4 chunks + 1 x bias chunk)
    for (int g = 0; g < 17; g++) {
        const int nch = (g < 16) ? 4 : 1;
        __syncthreads();   // previous group's reads done (and sX hoist done, for g=0)
        // stage nch chunks verbatim: contiguous, coalesced, conflict-free
        for (int r = 0; r < nch * 2; r++) {
            int o = r * 2048 + tid * 8;
            *(uint4*)&sB[o] = *(const uint4*)&Bt2[g * 16384 + o];
        }
        __syncthreads();

        for (int ch = 0; ch < nch; ch++) {
            const int kc = g * 4 + ch;
            const u16* bbase = sB + ch * 4096;
            short8 bfr[2][4];
            #pragma unroll
            for (int s = 0; s < 2; s++)
                #pragma unroll
                for (int c = 0; c < 4; c++)
                    bfr[s][c] = *(const short8*)(bbase + (s * 4 + c) * 512 + lane * 8);

            if (kc < 64) {
                float tk0 = b2f(sT[kc * 128 + wv * 32 + ll]);
                float tk1 = b2f(sT[kc * 128 + wv * 32 + 16 + ll]);
                #pragma unroll
                for (int s = 0; s < 2; s++) {
                    short8 a0, a1;
                    #pragma unroll
                    for (int j = 0; j < 8; j++) {
                        a0[j] = (short)f2b(tk0 * xsf[0][s][j]);
                        a1[j] = (short)f2b(tk1 * xsf[1][s][j]);
                    }
                    #pragma unroll
                    for (int c = 0; c < 4; c++) {
                        acc[0][c] = __builtin_amdgcn_mfma_f32_16x16x32_bf16(a0, bfr[s][c], acc[0][c], 0, 0, 0);
                        acc[1][c] = __builtin_amdgcn_mfma_f32_16x16x32_bf16(a1, bfr[s][c], acc[1][c], 0, 0, 0);
                    }
                }
            } else {
                // bias chunk: t = 1 -> A = xs (exact bf16 fragments)
                #pragma unroll
                for (int s = 0; s < 2; s++)
                    #pragma unroll
                    for (int c = 0; c < 4; c++) {
                        acc[0][c] = __builtin_amdgcn_mfma_f32_16x16x32_bf16(xab[0][s], bfr[s][c], acc[0][c], 0, 0, 0);
                        acc[1][c] = __builtin_amdgcn_mfma_f32_16x16x32_bf16(xab[1][s], bfr[s][c], acc[1][c], 0, 0, 0);
                    }
            }
        }
    }

    // epilogue: C row = quad*4+reg (edge), col = c*16+ll; scatter-add into agg[dst]
    #pragma unroll
    for (int rt = 0; rt < 2; rt++) {
        int elb = wv * 32 + rt * 16 + quad * 4;
        #pragma unroll
        for (int r = 0; r < 4; r++) {
            int el = elb + r;
            int eg = e0 + el;
            if (eg < NE) {
                int d = sDst[el];
                #pragma unroll
                for (int c = 0; c < 4; c++)
                    atomicAdd(&agg[d * 64 + c * 16 + ll], acc[rt][c][r]);
            }
        }
    }
}

// ---- GRU via MFMA (round-8 verified; staging vectorized) ---------------------------------
__global__ __launch_bounds__(256) void k_gru(const u16* __restrict__ x1b,
                                             const float* __restrict__ agg,
                                             const float* __restrict__ Wroot,
                                             const float* __restrict__ bconv,
                                             const float* __restrict__ Wi,
                                             const float* __restrict__ Wh,
                                             const float* __restrict__ bi,
                                             const float* __restrict__ bh,
                                             const int* __restrict__ batch,
                                             float* __restrict__ pooled) {
    __shared__ __align__(16) u16 sWi[192 * 72];
    __shared__ __align__(16) u16 sWh[192 * 72];
    __shared__ __align__(16) u16 sX2[64 * 72];
    __shared__ int sBatch[64];
    const int tid = threadIdx.x;
    const int lane = tid & 63, wv = tid >> 6;
    const int ll = lane & 15, quad = lane >> 4;
    const int n0 = blockIdx.x * 64;

    // stage WrT[n][k] = Wroot[k][n] (transpose), vectorized over k (ds_write_b64)
    for (int idx = tid; idx < 64 * 16; idx += 256) {
        int n = idx & 63, k4 = (idx >> 6) * 4;
        ushort4 a;
        a.x = f2b(Wroot[(k4 + 0) * 64 + n]);
        a.y = f2b(Wroot[(k4 + 1) * 64 + n]);
        a.z = f2b(Wroot[(k4 + 2) * 64 + n]);
        a.w = f2b(Wroot[(k4 + 3) * 64 + n]);
        *(ushort4*)&sWi[n * 72 + k4] = a;
    }
    if (tid < 64) {
        int n = n0 + tid;
        sBatch[tid] = (n < NN) ? batch[n] : -1;
    }
    __syncthreads();

    short8 ha[2];
    {
        int n = n0 + wv * 16 + ll;
        #pragma unroll
        for (int kc = 0; kc < 2; kc++) {
            if (n < NN) ha[kc] = *(const short8*)(x1b + n * 64 + kc * 32 + quad * 8);
            else        ha[kc] = (short8){0,0,0,0,0,0,0,0};
        }
    }
    f32x4 acc1[4];
    #pragma unroll
    for (int c = 0; c < 4; c++) acc1[c] = (f32x4){0.f, 0.f, 0.f, 0.f};
    #pragma unroll
    for (int kc = 0; kc < 2; kc++) {
        #pragma unroll
        for (int c = 0; c < 4; c++) {
            short8 b = *(const short8*)&sWi[(c * 16 + ll) * 72 + kc * 32 + quad * 8];
            acc1[c] = __builtin_amdgcn_mfma_f32_16x16x32_bf16(ha[kc], b, acc1[c], 0, 0, 0);
        }
    }
    #pragma unroll
    for (int c = 0; c < 4; c++) {
        int col = c * 16 + ll;
        float bcv = bconv[col];
        #pragma unroll
        for (int r = 0; r < 4; r++) {
            int row = wv * 16 + quad * 4 + r;
            int n = n0 + row;
            float v = 0.f;
            if (n < NN) v = fmaxf(acc1[c][r] + agg[n * 64 + col] + bcv, 0.f);
            sX2[row * 72 + col] = f2b(v);
        }
    }
    __syncthreads();

    // stage Wi/Wh vectorized (float4 coalesced loads -> ds_write_b64)
    for (int idx = tid; idx < 192 * 16; idx += 256) {
        int j = idx >> 4, i4 = (idx & 15) * 4;
        float4 wi4 = *(const float4*)&Wi[j * 64 + i4];
        float4 wh4 = *(const float4*)&Wh[j * 64 + i4];
        ushort4 a, b;
        a.x = f2b(wi4.x); a.y = f2b(wi4.y); a.z = f2b(wi4.z); a.w = f2b(wi4.w);
        b.x = f2b(wh4.x); b.y = f2b(wh4.y); b.z = f2b(wh4.z); b.w = f2b(wh4.w);
        *(ushort4*)&sWi[j * 72 + i4] = a;
        *(ushort4*)&sWh[j * 72 + i4] = b;
    }
    __syncthreads();

    short8 xa[2];
    #pragma unroll
    for (int kc = 0; kc < 2; kc++)
        xa[kc] = *(const short8*)&sX2[(wv * 16 + ll) * 72 + kc * 32 + quad * 8];

    f32x4 agi[12], agh[12];
    #pragma unroll
    for (int c = 0; c < 12; c++) { agi[c] = (f32x4){0.f,0.f,0.f,0.f}; agh[c] = (f32x4){0.f,0.f,0.f,0.f}; }
    #pragma unroll
    for (int kc = 0; kc < 2; kc++) {
        #pragma unroll
        for (int c = 0; c < 12; c++) {
            short8 bi8 = *(const short8*)&sWi[(c * 16 + ll) * 72 + kc * 32 + quad * 8];
            short8 bh8 = *(const short8*)&sWh[(c * 16 + ll) * 72 + kc * 32 + quad * 8];
            agi[c] = __builtin_amdgcn_mfma_f32_16x16x32_bf16(xa[kc], bi8, agi[c], 0, 0, 0);
            agh[c] = __builtin_amdgcn_mfma_f32_16x16x32_bf16(ha[kc], bh8, agh[c], 0, 0, 0);
        }
    }

    float hnv[4][4];
    #pragma unroll
    for (int c0 = 0; c0 < 4; c0++) {
        int d = c0 * 16 + ll;
        float bir = bi[d],        bhr = bh[d];
        float biz = bi[64 + d],   bhz = bh[64 + d];
        float bin = bi[128 + d],  bhn = bh[128 + d];
        #pragma unroll
        for (int r = 0; r < 4; r++) {
            int row = wv * 16 + quad * 4 + r;
            int n = n0 + row;
            float gir = agi[c0][r] + bir,     ghr = agh[c0][r] + bhr;
            float giz = agi[c0 + 4][r] + biz, ghz = agh[c0 + 4][r] + bhz;
            float gin = agi[c0 + 8][r] + bin, ghn = agh[c0 + 8][r] + bhn;
            float rg = 1.f / (1.f + __expf(-(gir + ghr)));
            float zg = 1.f / (1.f + __expf(-(giz + ghz)));
            float ng = tanhf(gin + rg * ghn);
            float hv = (n < NN) ? b2f(x1b[n * 64 + d]) : 0.f;
            hnv[c0][r] = (n < NN) ? ((1.f - zg) * ng + zg * hv) : 0.f;
        }
    }
    __syncthreads();

    float* hbuf = (float*)sWi;
    #pragma unroll
    for (int c0 = 0; c0 < 4; c0++) {
        int d = c0 * 16 + ll;
        #pragma unroll
        for (int r = 0; r < 4; r++) {
            int row = wv * 16 + quad * 4 + r;
            hbuf[row * 65 + d] = hnv[c0][r];
        }
    }
    __syncthreads();

    {
        int d = lane;
        float sum = 0.f;
        int pb = sBatch[wv * 16];
        #pragma unroll
        for (int rr = 0; rr < 16; rr++) {
            int row = wv * 16 + rr;
            int b = sBatch[row];
            float v = hbuf[row * 65 + d];
            if (b != pb) {
                if (pb >= 0) atomicAdd(&pooled[pb * 64 + d], sum);
                sum = v; pb = b;
            } else {
                sum += v;
            }
        }
        if (pb >= 0) atomicAdd(&pooled[pb * 64 + d], sum);
    }
}

// ---- heads: two 3-layer MLPs over pooled; output FLOAT32 ---------------------------------
__global__ __launch_bounds__(256) void k_heads(const float* __restrict__ pooled,
                                               const float* __restrict__ W11, const float* __restrict__ b11,
                                               const float* __restrict__ W12, const float* __restrict__ b12,
                                               const float* __restrict__ W13, const float* __restrict__ b13,
                                               const float* __restrict__ W21, const float* __restrict__ b21,
                                               const float* __restrict__ W22, const float* __restrict__ b22,
                                               const float* __restrict__ W23, const float* __restrict__ b23,
                                               float* __restrict__ out) {
    __shared__ float sV[4][64];
    __shared__ float sA[4][64];
    int tid = threadIdx.x, lane = tid & 63, wv = tid >> 6;
    int g = blockIdx.x * 4 + wv;
    if (g >= NG) return;
    float p = pooled[g * 64 + lane];
    sV[wv][lane] = p;
    float y[2];
    const float* W1s[2] = {W11, W21}; const float* b1s[2] = {b11, b21};
    const float* W2s[2] = {W12, W22}; const float* b2s[2] = {b12, b22};
    const float* W3s[2] = {W13, W23}; const float* b3s[2] = {b13, b23};
    #pragma unroll
    for (int hd = 0; hd < 2; hd++) {
        float a = b1s[hd][lane];
        #pragma unroll 8
        for (int i = 0; i < 64; i++) a += sV[wv][i] * W1s[hd][i * 64 + lane];
        a = fmaxf(a, 0.f);
        sA[wv][lane] = a;
        float a2 = b2s[hd][lane];
        #pragma unroll 8
        for (int i = 0; i < 64; i++) a2 += sA[wv][i] * W2s[hd][i * 64 + lane];
        a2 = fmaxf(a2, 0.f);
        float part = a2 * W3s[hd][lane];
        #pragma unroll
        for (int m = 32; m > 0; m >>= 1) part += __shfl_xor(part, m, 64);
        y[hd] = part + b3s[hd][0];
    }
    if (lane == 0) {
        out[g * 2 + 0] = y[0];
        out[g * 2 + 1] = y[1];
    }
}

extern "C" void kernel_launch(void* const* d_in, const int* in_sizes, int n_in,
                              void* d_out, int out_size, void* d_ws, size_t ws_size,
                              hipStream_t stream) {
    const float* x     = (const float*)d_in[0];
    const int* eidx    = (const int*)d_in[1];
    const float* ea    = (const float*)d_in[2];
    const int* batch   = (const int*)d_in[3];
    const float* W0    = (const float*)d_in[4];  const float* b0    = (const float*)d_in[5];
    const float* We1   = (const float*)d_in[6];  const float* be1   = (const float*)d_in[7];
    const float* We2   = (const float*)d_in[8];  const float* be2   = (const float*)d_in[9];
    const float* Wroot = (const float*)d_in[10]; const float* bconv = (const float*)d_in[11];
    const float* Wi    = (const float*)d_in[12]; const float* Wh    = (const float*)d_in[13];
    const float* bi    = (const float*)d_in[14]; const float* bh    = (const float*)d_in[15];
    const float* W11   = (const float*)d_in[16]; const float* b11   = (const float*)d_in[17];
    const float* W12   = (const float*)d_in[18]; const float* b12   = (const float*)d_in[19];
    const float* W13   = (const float*)d_in[20]; const float* b13   = (const float*)d_in[21];
    const float* W21   = (const float*)d_in[22]; const float* b21   = (const float*)d_in[23];
    const float* W22   = (const float*)d_in[24]; const float* b22   = (const float*)d_in[25];
    const float* W23   = (const float*)d_in[26]; const float* b23   = (const float*)d_in[27];
    float* out = (float*)d_out;

    // workspace: total 10,388,480 B
    char* ws = (char*)d_ws;
    float* agg    = (float*)(ws);                       // 6,400,000 B
    u16*   x1b    = (u16*)(ws + 6400000);               // 3,200,000 B
    u16*   Bt2    = (u16*)(ws + 9600000);               //   532,480 B
    float* pooled = (float*)(ws + 10132480);            //   256,000 B

    hipLaunchKernelGGL(k_pre, dim3(7274), dim3(256), 0, stream,
                       x, W0, b0, x1b, We2, be2, agg, pooled, Bt2);
    hipLaunchKernelGGL(k_msg, dim3(782), dim3(256), 0, stream, ea, eidx, We1, be1, x1b, Bt2, agg);
    hipLaunchKernelGGL(k_gru, dim3(391), dim3(256), 0, stream, x1b, agg, Wroot, bconv,
                       Wi, Wh, bi, bh, batch, pooled);
    hipLaunchKernelGGL(k_heads, dim3(250), dim3(256), 0, stream, pooled,
                       W11, b11, W12, b12, W13, b13, W21, b21, W22, b22, W23, b23, out);
}

// Round 12
// 237.198 us; speedup vs baseline: 1.1442x; 1.1442x over previous
//
#include <hip/hip_runtime.h>
#include <hip/hip_bf16.h>

#define NN 25000
#define NE 100000
#define FIN 32
#define DD 64
#define NG 1000

typedef unsigned short u16;
typedef __attribute__((ext_vector_type(8))) short short8;
typedef __attribute__((ext_vector_type(4))) float f32x4;

__device__ __forceinline__ float b2f(u16 u) {
    union { unsigned int i; float f; } v; v.i = ((unsigned int)u) << 16; return v.f;
}
__device__ __forceinline__ u16 f2b(float f) {
    __hip_bfloat16 h = __float2bfloat16(f);
    return __builtin_bit_cast(u16, h);
}
// edge_index may be int64 read as int32 words: odd words would all be 0.
__device__ __forceinline__ bool idx_is_i64(const int* e) {
    return (e[1] == 0) & (e[3] == 0) & (e[5] == 0) & (e[7] == 0) & (e[9] == 0);
}
__device__ __forceinline__ int ld_src(const int* e, int i, bool i64) {
    return i64 ? e[2 * i] : e[i];
}
__device__ __forceinline__ int ld_dst(const int* e, int i, bool i64) {
    return i64 ? e[2 * (NE + i)] : e[NE + i];
}

// ---- fused pre-pass: blocks [0,6250) = lin0; blocks [6250,7274) = Bt2 build + zeroing ----
// Bt2 fragment-major: idx = kc*4096 + (s*4+c)*512 + lane*8 + j  holds
// B[k = kc*64 + s*32 + (lane>>4)*8 + j][o = c*16 + (lane&15)]  (r>=4096 -> be2 rows).
__global__ __launch_bounds__(256) void k_pre(const float* __restrict__ x,
                                             const float* __restrict__ W0,
                                             const float* __restrict__ b0,
                                             u16* __restrict__ x1b,
                                             const float* __restrict__ We2,
                                             const float* __restrict__ be2,
                                             float* __restrict__ agg,
                                             float* __restrict__ pooled,
                                             u16* __restrict__ Bt2) {
    __shared__ float sW[FIN * DD];
    __shared__ float sx[4 * FIN];
    if (blockIdx.x < 6250) {
        int tid = threadIdx.x;
        for (int i = tid; i < FIN * DD; i += 256) sW[i] = W0[i];
        int nbase = blockIdx.x * 4;
        for (int i = tid; i < 4 * FIN; i += 256) {
            int nl = i >> 5, f = i & 31;
            int n = nbase + nl;
            sx[i] = (n < NN) ? x[n * FIN + f] : 0.f;
        }
        __syncthreads();
        int lane = tid & 63, nl = tid >> 6;
        int n = nbase + nl;
        if (n < NN) {
            float acc = b0[lane];
            #pragma unroll
            for (int f = 0; f < FIN; f++) acc += sx[nl * FIN + f] * sW[f * DD + lane];
            x1b[n * DD + lane] = f2b(fmaxf(acc, 0.f));
        }
    } else {
        int tid = (blockIdx.x - 6250) * 256 + threadIdx.x;
        int stride = 1024 * 256;
        for (int idx = tid; idx < 65 * 4096; idx += stride) {
            int kc = idx >> 12;
            int rem = idx & 4095;
            int f = rem >> 9;
            int ln = (rem >> 3) & 63;
            int j = idx & 7;
            int s = f >> 2, c = f & 3;
            int o = c * 16 + (ln & 15);
            int r = kc * 64 + s * 32 + (ln >> 4) * 8 + j;
            float v = (r < 4096) ? We2[(r >> 6) * 4096 + (r & 63) * 64 + o]
                                 : be2[(r - 4096) * 64 + o];
            Bt2[idx] = f2b(v);
        }
        for (int idx = tid; idx < NN * DD; idx += stride) agg[idx] = 0.f;
        for (int idx = tid; idx < NG * DD; idx += stride) pooled[idx] = 0.f;
    }
}

// ---- fused NNConv message GEMM + scatter -------------------------------------------------
// 512 threads = 8 waves: wave = (row-half rh, col-quarter cq). Per kc: q = Xs@W2[kc]
// (bf16 MFMA, fixed A-frags), msg += t[e,kc]*q (f32). B-frags loaded coalesced direct
// from L2-resident Bt2 with depth-1 register prefetch; K-loop barrier-free.
// LDS: sX 18432 + sT 16384 + sWe1 2048 + sbe1 256 + sDst 512 = 37632 B -> 3-4 blocks/CU.
__global__ __launch_bounds__(512, 4) void k_msg(const float* __restrict__ ea,
                                                const int* __restrict__ eidx,
                                                const float* __restrict__ We1,
                                                const float* __restrict__ be1,
                                                const u16* __restrict__ x1b,
                                                const u16* __restrict__ Bt2,
                                                float* __restrict__ agg) {
    __shared__ __align__(16) u16 sX[128 * 72];  // gathered x1 rows (bf16), pad 72
    __shared__ u16 sT[64 * 128];                // t transposed [k][e], bf16
    __shared__ float sWe1[8 * 64];
    __shared__ float sbe1[64];
    __shared__ int sDst[128];
    const int tid = threadIdx.x;
    const int lane = tid & 63, wv = tid >> 6;
    const int ll = lane & 15, quad = lane >> 4;
    const int rh = wv >> 2, cq = wv & 3;       // row-half, col-quarter
    const int e0 = blockIdx.x * 128;
    const bool i64 = idx_is_i64(eidx);

    if (tid < 512) sWe1[tid] = We1[tid];
    if (tid < 64) sbe1[tid] = be1[tid];
    if (tid < 128) sDst[tid] = (e0 + tid < NE) ? ld_dst(eidx, e0 + tid, i64) : 0;

    // phase 1: gather x1 rows (bf16) for 128 edges; each thread: 32 B of one row
    const int el4 = tid >> 2, seg = tid & 3;
    const int eg4 = e0 + el4;
    {
        if (eg4 < NE) {
            int sv = ld_src(eidx, eg4, i64);
            const u16* xr = x1b + sv * 64 + seg * 16;
            *(uint4*)&sX[el4 * 72 + seg * 16]     = *(const uint4*)(xr);
            *(uint4*)&sX[el4 * 72 + seg * 16 + 8] = *(const uint4*)(xr + 8);
        } else {
            uint4 z = make_uint4(0, 0, 0, 0);
            *(uint4*)&sX[el4 * 72 + seg * 16]     = z;
            *(uint4*)&sX[el4 * 72 + seg * 16 + 8] = z;
        }
    }
    float eav[8];
    if (eg4 < NE) {
        f32x4 v0 = *(const f32x4*)(ea + eg4 * 8);
        f32x4 v1 = *(const f32x4*)(ea + eg4 * 8 + 4);
        #pragma unroll
        for (int f = 0; f < 4; f++) { eav[f] = v0[f]; eav[4 + f] = v1[f]; }
    } else {
        #pragma unroll
        for (int f = 0; f < 8; f++) eav[f] = 0.f;
    }
    __syncthreads();

    // phase 2: t[e,k] = relu(ea @ We1 + be1); each thread: 16 k-values of its edge
    {
        int k0 = seg * 16;
        for (int kk = 0; kk < 16; kk++) {
            int k = k0 + kk;
            float acc = sbe1[k];
            #pragma unroll
            for (int f = 0; f < 8; f++) acc += eav[f] * sWe1[f * 64 + k];
            sT[k * 128 + el4] = (eg4 < NE) ? f2b(fmaxf(acc, 0.f)) : (u16)0;
        }
    }
    __syncthreads();   // last barrier — K-loop below is barrier-free

    // fixed A-fragments: this wave's 4 row-tiles (rows rh*64 .. rh*64+63)
    short8 xa[4][2];
    #pragma unroll
    for (int rt = 0; rt < 4; rt++)
        #pragma unroll
        for (int s = 0; s < 2; s++)
            xa[rt][s] = *(const short8*)&sX[(rh * 64 + rt * 16 + ll) * 72 + s * 32 + quad * 8];

    f32x4 msg[4];
    #pragma unroll
    for (int rt = 0; rt < 4; rt++) msg[rt] = (f32x4){0.f, 0.f, 0.f, 0.f};

    // coalesced per-lane B pointers for this wave's column quarter
    const u16* gB0 = Bt2 + (0 * 4 + cq) * 512 + lane * 8;
    const u16* gB1 = Bt2 + (1 * 4 + cq) * 512 + lane * 8;

    short8 bf0 = *(const short8*)gB0;
    short8 bf1 = *(const short8*)gB1;
    const f32x4 zero = (f32x4){0.f, 0.f, 0.f, 0.f};

    for (int kc = 0; kc < 64; kc++) {
        short8 bn0 = *(const short8*)(gB0 + (kc + 1) * 4096);
        short8 bn1 = *(const short8*)(gB1 + (kc + 1) * 4096);

        float tk[4][4];
        #pragma unroll
        for (int rt = 0; rt < 4; rt++) {
            const u16* tp = &sT[kc * 128 + rh * 64 + rt * 16 + quad * 4];
            #pragma unroll
            for (int r = 0; r < 4; r++) tk[rt][r] = b2f(tp[r]);
        }

        #pragma unroll
        for (int rt = 0; rt < 4; rt++) {
            f32x4 q = __builtin_amdgcn_mfma_f32_16x16x32_bf16(xa[rt][0], bf0, zero, 0, 0, 0);
            q = __builtin_amdgcn_mfma_f32_16x16x32_bf16(xa[rt][1], bf1, q, 0, 0, 0);
            #pragma unroll
            for (int r = 0; r < 4; r++) msg[rt][r] += tk[rt][r] * q[r];
        }
        bf0 = bn0; bf1 = bn1;
    }
    // bias chunk (kc=64): t = 1 -> msg += q
    #pragma unroll
    for (int rt = 0; rt < 4; rt++) {
        f32x4 q = __builtin_amdgcn_mfma_f32_16x16x32_bf16(xa[rt][0], bf0, zero, 0, 0, 0);
        q = __builtin_amdgcn_mfma_f32_16x16x32_bf16(xa[rt][1], bf1, q, 0, 0, 0);
        #pragma unroll
        for (int r = 0; r < 4; r++) msg[rt][r] += q[r];
    }

    // epilogue: row = rh*64 + rt*16 + quad*4 + r, col = cq*16 + ll; scatter into agg[dst]
    #pragma unroll
    for (int rt = 0; rt < 4; rt++) {
        #pragma unroll
        for (int r = 0; r < 4; r++) {
            int el = rh * 64 + rt * 16 + quad * 4 + r;
            int eg = e0 + el;
            if (eg < NE) {
                int d = sDst[el];
                atomicAdd(&agg[d * 64 + cq * 16 + ll], msg[rt][r]);
            }
        }
    }
}

// ---- GRU via MFMA (round-8 verified; staging vectorized) ---------------------------------
__global__ __launch_bounds__(256) void k_gru(const u16* __restrict__ x1b,
                                             const float* __restrict__ agg,
                                             const float* __restrict__ Wroot,
                                             const float* __restrict__ bconv,
                                             const float* __restrict__ Wi,
                                             const float* __restrict__ Wh,
                                             const float* __restrict__ bi,
                                             const float* __restrict__ bh,
                                             const int* __restrict__ batch,
                                             float* __restrict__ pooled) {
    __shared__ __align__(16) u16 sWi[192 * 72];
    __shared__ __align__(16) u16 sWh[192 * 72];
    __shared__ __align__(16) u16 sX2[64 * 72];
    __shared__ int sBatch[64];
    const int tid = threadIdx.x;
    const int lane = tid & 63, wv = tid >> 6;
    const int ll = lane & 15, quad = lane >> 4;
    const int n0 = blockIdx.x * 64;

    for (int idx = tid; idx < 64 * 16; idx += 256) {
        int n = idx & 63, k4 = (idx >> 6) * 4;
        ushort4 a;
        a.x = f2b(Wroot[(k4 + 0) * 64 + n]);
        a.y = f2b(Wroot[(k4 + 1) * 64 + n]);
        a.z = f2b(Wroot[(k4 + 2) * 64 + n]);
        a.w = f2b(Wroot[(k4 + 3) * 64 + n]);
        *(ushort4*)&sWi[n * 72 + k4] = a;
    }
    if (tid < 64) {
        int n = n0 + tid;
        sBatch[tid] = (n < NN) ? batch[n] : -1;
    }
    __syncthreads();

    short8 ha[2];
    {
        int n = n0 + wv * 16 + ll;
        #pragma unroll
        for (int kc = 0; kc < 2; kc++) {
            if (n < NN) ha[kc] = *(const short8*)(x1b + n * 64 + kc * 32 + quad * 8);
            else        ha[kc] = (short8){0,0,0,0,0,0,0,0};
        }
    }
    f32x4 acc1[4];
    #pragma unroll
    for (int c = 0; c < 4; c++) acc1[c] = (f32x4){0.f, 0.f, 0.f, 0.f};
    #pragma unroll
    for (int kc = 0; kc < 2; kc++) {
        #pragma unroll
        for (int c = 0; c < 4; c++) {
            short8 b = *(const short8*)&sWi[(c * 16 + ll) * 72 + kc * 32 + quad * 8];
            acc1[c] = __builtin_amdgcn_mfma_f32_16x16x32_bf16(ha[kc], b, acc1[c], 0, 0, 0);
        }
    }
    #pragma unroll
    for (int c = 0; c < 4; c++) {
        int col = c * 16 + ll;
        float bcv = bconv[col];
        #pragma unroll
        for (int r = 0; r < 4; r++) {
            int row = wv * 16 + quad * 4 + r;
            int n = n0 + row;
            float v = 0.f;
            if (n < NN) v = fmaxf(acc1[c][r] + agg[n * 64 + col] + bcv, 0.f);
            sX2[row * 72 + col] = f2b(v);
        }
    }
    __syncthreads();

    for (int idx = tid; idx < 192 * 16; idx += 256) {
        int j = idx >> 4, i4 = (idx & 15) * 4;
        float4 wi4 = *(const float4*)&Wi[j * 64 + i4];
        float4 wh4 = *(const float4*)&Wh[j * 64 + i4];
        ushort4 a, b;
        a.x = f2b(wi4.x); a.y = f2b(wi4.y); a.z = f2b(wi4.z); a.w = f2b(wi4.w);
        b.x = f2b(wh4.x); b.y = f2b(wh4.y); b.z = f2b(wh4.z); b.w = f2b(wh4.w);
        *(ushort4*)&sWi[j * 72 + i4] = a;
        *(ushort4*)&sWh[j * 72 + i4] = b;
    }
    __syncthreads();

    short8 xa[2];
    #pragma unroll
    for (int kc = 0; kc < 2; kc++)
        xa[kc] = *(const short8*)&sX2[(wv * 16 + ll) * 72 + kc * 32 + quad * 8];

    f32x4 agi[12], agh[12];
    #pragma unroll
    for (int c = 0; c < 12; c++) { agi[c] = (f32x4){0.f,0.f,0.f,0.f}; agh[c] = (f32x4){0.f,0.f,0.f,0.f}; }
    #pragma unroll
    for (int kc = 0; kc < 2; kc++) {
        #pragma unroll
        for (int c = 0; c < 12; c++) {
            short8 bi8 = *(const short8*)&sWi[(c * 16 + ll) * 72 + kc * 32 + quad * 8];
            short8 bh8 = *(const short8*)&sWh[(c * 16 + ll) * 72 + kc * 32 + quad * 8];
            agi[c] = __builtin_amdgcn_mfma_f32_16x16x32_bf16(xa[kc], bi8, agi[c], 0, 0, 0);
            agh[c] = __builtin_amdgcn_mfma_f32_16x16x32_bf16(ha[kc], bh8, agh[c], 0, 0, 0);
        }
    }

    float hnv[4][4];
    #pragma unroll
    for (int c0 = 0; c0 < 4; c0++) {
        int d = c0 * 16 + ll;
        float bir = bi[d],        bhr = bh[d];
        float biz = bi[64 + d],   bhz = bh[64 + d];
        float bin = bi[128 + d],  bhn = bh[128 + d];
        #pragma unroll
        for (int r = 0; r < 4; r++) {
            int row = wv * 16 + quad * 4 + r;
            int n = n0 + row;
            float gir = agi[c0][r] + bir,     ghr = agh[c0][r] + bhr;
            float giz = agi[c0 + 4][r] + biz, ghz = agh[c0 + 4][r] + bhz;
            float gin = agi[c0 + 8][r] + bin, ghn = agh[c0 + 8][r] + bhn;
            float rg = 1.f / (1.f + __expf(-(gir + ghr)));
            float zg = 1.f / (1.f + __expf(-(giz + ghz)));
            float ng = tanhf(gin + rg * ghn);
            float hv = (n < NN) ? b2f(x1b[n * 64 + d]) : 0.f;
            hnv[c0][r] = (n < NN) ? ((1.f - zg) * ng + zg * hv) : 0.f;
        }
    }
    __syncthreads();

    float* hbuf = (float*)sWi;
    #pragma unroll
    for (int c0 = 0; c0 < 4; c0++) {
        int d = c0 * 16 + ll;
        #pragma unroll
        for (int r = 0; r < 4; r++) {
            int row = wv * 16 + quad * 4 + r;
            hbuf[row * 65 + d] = hnv[c0][r];
        }
    }
    __syncthreads();

    {
        int d = lane;
        float sum = 0.f;
        int pb = sBatch[wv * 16];
        #pragma unroll
        for (int rr = 0; rr < 16; rr++) {
            int row = wv * 16 + rr;
            int b = sBatch[row];
            float v = hbuf[row * 65 + d];
            if (b != pb) {
                if (pb >= 0) atomicAdd(&pooled[pb * 64 + d], sum);
                sum = v; pb = b;
            } else {
                sum += v;
            }
        }
        if (pb >= 0) atomicAdd(&pooled[pb * 64 + d], sum);
    }
}

// ---- heads: two 3-layer MLPs over pooled; output FLOAT32 ---------------------------------
__global__ __launch_bounds__(256) void k_heads(const float* __restrict__ pooled,
                                               const float* __restrict__ W11, const float* __restrict__ b11,
                                               const float* __restrict__ W12, const float* __restrict__ b12,
                                               const float* __restrict__ W13, const float* __restrict__ b13,
                                               const float* __restrict__ W21, const float* __restrict__ b21,
                                               const float* __restrict__ W22, const float* __restrict__ b22,
                                               const float* __restrict__ W23, const float* __restrict__ b23,
                                               float* __restrict__ out) {
    __shared__ float sV[4][64];
    __shared__ float sA[4][64];
    int tid = threadIdx.x, lane = tid & 63, wv = tid >> 6;
    int g = blockIdx.x * 4 + wv;
    if (g >= NG) return;
    float p = pooled[g * 64 + lane];
    sV[wv][lane] = p;
    float y[2];
    const float* W1s[2] = {W11, W21}; const float* b1s[2] = {b11, b21};
    const float* W2s[2] = {W12, W22}; const float* b2s[2] = {b12, b22};
    const float* W3s[2] = {W13, W23}; const float* b3s[2] = {b13, b23};
    #pragma unroll
    for (int hd = 0; hd < 2; hd++) {
        float a = b1s[hd][lane];
        #pragma unroll 8
        for (int i = 0; i < 64; i++) a += sV[wv][i] * W1s[hd][i * 64 + lane];
        a = fmaxf(a, 0.f);
        sA[wv][lane] = a;
        float a2 = b2s[hd][lane];
        #pragma unroll 8
        for (int i = 0; i < 64; i++) a2 += sA[wv][i] * W2s[hd][i * 64 + lane];
        a2 = fmaxf(a2, 0.f);
        float part = a2 * W3s[hd][lane];
        #pragma unroll
        for (int m = 32; m > 0; m >>= 1) part += __shfl_xor(part, m, 64);
        y[hd] = part + b3s[hd][0];
    }
    if (lane == 0) {
        out[g * 2 + 0] = y[0];
        out[g * 2 + 1] = y[1];
    }
}

extern "C" void kernel_launch(void* const* d_in, const int* in_sizes, int n_in,
                              void* d_out, int out_size, void* d_ws, size_t ws_size,
                              hipStream_t stream) {
    const float* x     = (const float*)d_in[0];
    const int* eidx    = (const int*)d_in[1];
    const float* ea    = (const float*)d_in[2];
    const int* batch   = (const int*)d_in[3];
    const float* W0    = (const float*)d_in[4];  const float* b0    = (const float*)d_in[5];
    const float* We1   = (const float*)d_in[6];  const float* be1   = (const float*)d_in[7];
    const float* We2   = (const float*)d_in[8];  const float* be2   = (const float*)d_in[9];
    const float* Wroot = (const float*)d_in[10]; const float* bconv = (const float*)d_in[11];
    const float* Wi    = (const float*)d_in[12]; const float* Wh    = (const float*)d_in[13];
    const float* bi    = (const float*)d_in[14]; const float* bh    = (const float*)d_in[15];
    const float* W11   = (const float*)d_in[16]; const float* b11   = (const float*)d_in[17];
    const float* W12   = (const float*)d_in[18]; const float* b12   = (const float*)d_in[19];
    const float* W13   = (const float*)d_in[20]; const float* b13   = (const float*)d_in[21];
    const float* W21   = (const float*)d_in[22]; const float* b21   = (const float*)d_in[23];
    const float* W22   = (const float*)d_in[24]; const float* b22   = (const float*)d_in[25];
    const float* W23   = (const float*)d_in[26]; const float* b23   = (const float*)d_in[27];
    float* out = (float*)d_out;

    // workspace: total 10,388,480 B
    char* ws = (char*)d_ws;
    float* agg    = (float*)(ws);                       // 6,400,000 B
    u16*   x1b    = (u16*)(ws + 6400000);               // 3,200,000 B
    u16*   Bt2    = (u16*)(ws + 9600000);               //   532,480 B
    float* pooled = (float*)(ws + 10132480);            //   256,000 B

    hipLaunchKernelGGL(k_pre, dim3(7274), dim3(256), 0, stream,
                       x, W0, b0, x1b, We2, be2, agg, pooled, Bt2);
    hipLaunchKernelGGL(k_msg, dim3(782), dim3(512), 0, stream, ea, eidx, We1, be1, x1b, Bt2, agg);
    hipLaunchKernelGGL(k_gru, dim3(391), dim3(256), 0, stream, x1b, agg, Wroot, bconv,
                       Wi, Wh, bi, bh, batch, pooled);
    hipLaunchKernelGGL(k_heads, dim3(250), dim3(256), 0, stream, pooled,
                       W11, b11, W12, b12, W13, b13, W21, b21, W22, b22, W23, b23, out);
}

// Round 13
// 235.956 us; speedup vs baseline: 1.1502x; 1.0053x over previous
//
#include <hip/hip_runtime.h>
#include <hip/hip_bf16.h>

#define NN 25000
#define NE 100000
#define FIN 32
#define DD 64
#define NG 1000

typedef unsigned short u16;
typedef __attribute__((ext_vector_type(8))) short short8;
typedef __attribute__((ext_vector_type(4))) float f32x4;

__device__ __forceinline__ float b2f(u16 u) {
    union { unsigned int i; float f; } v; v.i = ((unsigned int)u) << 16; return v.f;
}
__device__ __forceinline__ u16 f2b(float f) {
    __hip_bfloat16 h = __float2bfloat16(f);
    return __builtin_bit_cast(u16, h);
}
// edge_index may be int64 read as int32 words: odd words would all be 0.
__device__ __forceinline__ bool idx_is_i64(const int* e) {
    return (e[1] == 0) & (e[3] == 0) & (e[5] == 0) & (e[7] == 0) & (e[9] == 0);
}
__device__ __forceinline__ int ld_src(const int* e, int i, bool i64) {
    return i64 ? e[2 * i] : e[i];
}
__device__ __forceinline__ int ld_dst(const int* e, int i, bool i64) {
    return i64 ? e[2 * (NE + i)] : e[NE + i];
}

// ---- fused pre-pass: blocks [0,6250) = lin0; blocks [6250,7274) = Bt2 build + zeroing ----
// Bt2 fragment-major: idx = kc*4096 + (s*4+c)*512 + lane*8 + j  holds
// B[k = kc*64 + s*32 + (lane>>4)*8 + j][o = c*16 + (lane&15)]  (r>=4096 -> be2 rows).
__global__ __launch_bounds__(256) void k_pre(const float* __restrict__ x,
                                             const float* __restrict__ W0,
                                             const float* __restrict__ b0,
                                             u16* __restrict__ x1b,
                                             const float* __restrict__ We2,
                                             const float* __restrict__ be2,
                                             float* __restrict__ agg,
                                             float* __restrict__ pooled,
                                             u16* __restrict__ Bt2) {
    __shared__ float sW[FIN * DD];
    __shared__ float sx[4 * FIN];
    if (blockIdx.x < 6250) {
        int tid = threadIdx.x;
        for (int i = tid; i < FIN * DD; i += 256) sW[i] = W0[i];
        int nbase = blockIdx.x * 4;
        for (int i = tid; i < 4 * FIN; i += 256) {
            int nl = i >> 5, f = i & 31;
            int n = nbase + nl;
            sx[i] = (n < NN) ? x[n * FIN + f] : 0.f;
        }
        __syncthreads();
        int lane = tid & 63, nl = tid >> 6;
        int n = nbase + nl;
        if (n < NN) {
            float acc = b0[lane];
            #pragma unroll
            for (int f = 0; f < FIN; f++) acc += sx[nl * FIN + f] * sW[f * DD + lane];
            x1b[n * DD + lane] = f2b(fmaxf(acc, 0.f));
        }
    } else {
        int tid = (blockIdx.x - 6250) * 256 + threadIdx.x;
        int stride = 1024 * 256;
        for (int idx = tid; idx < 65 * 4096; idx += stride) {
            int kc = idx >> 12;
            int rem = idx & 4095;
            int f = rem >> 9;
            int ln = (rem >> 3) & 63;
            int j = idx & 7;
            int s = f >> 2, c = f & 3;
            int o = c * 16 + (ln & 15);
            int r = kc * 64 + s * 32 + (ln >> 4) * 8 + j;
            float v = (r < 4096) ? We2[(r >> 6) * 4096 + (r & 63) * 64 + o]
                                 : be2[(r - 4096) * 64 + o];
            Bt2[idx] = f2b(v);
        }
        for (int idx = tid; idx < NN * DD; idx += stride) agg[idx] = 0.f;
        for (int idx = tid; idx < NG * DD; idx += stride) pooled[idx] = 0.f;
    }
}

// ---- fused NNConv message GEMM + scatter -------------------------------------------------
// 512 threads = 8 waves: wave = (row-half rh, col-quarter cq). Per kc: q = Xs@W2[kc]
// (bf16 MFMA, fixed A-frags), msg += t[e,kc]*q (f32; t read as ONE float4 per row-tile).
// B-frags loaded coalesced direct from L2-resident Bt2 with depth-1 register prefetch;
// K-loop barrier-free. LDS: sX 18432 + sT(f32) 32768 + 2048 + 256 + 512 = 54016 B.
__global__ __launch_bounds__(512, 4) void k_msg(const float* __restrict__ ea,
                                                const int* __restrict__ eidx,
                                                const float* __restrict__ We1,
                                                const float* __restrict__ be1,
                                                const u16* __restrict__ x1b,
                                                const u16* __restrict__ Bt2,
                                                float* __restrict__ agg) {
    __shared__ __align__(16) u16 sX[128 * 72];   // gathered x1 rows (bf16), pad 72
    __shared__ __align__(16) float sT[64 * 128]; // t transposed [k][e], f32
    __shared__ float sWe1[8 * 64];
    __shared__ float sbe1[64];
    __shared__ int sDst[128];
    const int tid = threadIdx.x;
    const int lane = tid & 63, wv = tid >> 6;
    const int ll = lane & 15, quad = lane >> 4;
    const int rh = wv >> 2, cq = wv & 3;       // row-half, col-quarter
    const int e0 = blockIdx.x * 128;
    const bool i64 = idx_is_i64(eidx);

    if (tid < 512) sWe1[tid] = We1[tid];
    if (tid < 64) sbe1[tid] = be1[tid];
    if (tid < 128) sDst[tid] = (e0 + tid < NE) ? ld_dst(eidx, e0 + tid, i64) : 0;

    // phase 1: gather x1 rows (bf16) for 128 edges; each thread: 32 B of one row
    const int el4 = tid >> 2, seg = tid & 3;
    const int eg4 = e0 + el4;
    {
        if (eg4 < NE) {
            int sv = ld_src(eidx, eg4, i64);
            const u16* xr = x1b + sv * 64 + seg * 16;
            *(uint4*)&sX[el4 * 72 + seg * 16]     = *(const uint4*)(xr);
            *(uint4*)&sX[el4 * 72 + seg * 16 + 8] = *(const uint4*)(xr + 8);
        } else {
            uint4 z = make_uint4(0, 0, 0, 0);
            *(uint4*)&sX[el4 * 72 + seg * 16]     = z;
            *(uint4*)&sX[el4 * 72 + seg * 16 + 8] = z;
        }
    }
    float eav[8];
    if (eg4 < NE) {
        f32x4 v0 = *(const f32x4*)(ea + eg4 * 8);
        f32x4 v1 = *(const f32x4*)(ea + eg4 * 8 + 4);
        #pragma unroll
        for (int f = 0; f < 4; f++) { eav[f] = v0[f]; eav[4 + f] = v1[f]; }
    } else {
        #pragma unroll
        for (int f = 0; f < 8; f++) eav[f] = 0.f;
    }
    __syncthreads();

    // phase 2: t[e,k] = relu(ea @ We1 + be1); each thread: 16 k-values of its edge (f32)
    {
        int k0 = seg * 16;
        for (int kk = 0; kk < 16; kk++) {
            int k = k0 + kk;
            float acc = sbe1[k];
            #pragma unroll
            for (int f = 0; f < 8; f++) acc += eav[f] * sWe1[f * 64 + k];
            sT[k * 128 + el4] = (eg4 < NE) ? fmaxf(acc, 0.f) : 0.f;
        }
    }
    __syncthreads();   // last barrier — K-loop below is barrier-free

    // fixed A-fragments: this wave's 4 row-tiles (rows rh*64 .. rh*64+63)
    short8 xa[4][2];
    #pragma unroll
    for (int rt = 0; rt < 4; rt++)
        #pragma unroll
        for (int s = 0; s < 2; s++)
            xa[rt][s] = *(const short8*)&sX[(rh * 64 + rt * 16 + ll) * 72 + s * 32 + quad * 8];

    f32x4 msg[4];
    #pragma unroll
    for (int rt = 0; rt < 4; rt++) msg[rt] = (f32x4){0.f, 0.f, 0.f, 0.f};

    // coalesced per-lane B pointers for this wave's column quarter
    const u16* gB0 = Bt2 + (0 * 4 + cq) * 512 + lane * 8;
    const u16* gB1 = Bt2 + (1 * 4 + cq) * 512 + lane * 8;

    short8 bf0 = *(const short8*)gB0;
    short8 bf1 = *(const short8*)gB1;
    const f32x4 zero = (f32x4){0.f, 0.f, 0.f, 0.f};

    for (int kc = 0; kc < 64; kc++) {
        short8 bn0 = *(const short8*)(gB0 + (kc + 1) * 4096);
        short8 bn1 = *(const short8*)(gB1 + (kc + 1) * 4096);

        f32x4 tk[4];
        #pragma unroll
        for (int rt = 0; rt < 4; rt++)
            tk[rt] = *(const f32x4*)&sT[kc * 128 + rh * 64 + rt * 16 + quad * 4];

        #pragma unroll
        for (int rt = 0; rt < 4; rt++) {
            f32x4 q = __builtin_amdgcn_mfma_f32_16x16x32_bf16(xa[rt][0], bf0, zero, 0, 0, 0);
            q = __builtin_amdgcn_mfma_f32_16x16x32_bf16(xa[rt][1], bf1, q, 0, 0, 0);
            #pragma unroll
            for (int r = 0; r < 4; r++) msg[rt][r] += tk[rt][r] * q[r];
        }
        bf0 = bn0; bf1 = bn1;
    }
    // bias chunk (kc=64): t = 1 -> msg += q
    #pragma unroll
    for (int rt = 0; rt < 4; rt++) {
        f32x4 q = __builtin_amdgcn_mfma_f32_16x16x32_bf16(xa[rt][0], bf0, zero, 0, 0, 0);
        q = __builtin_amdgcn_mfma_f32_16x16x32_bf16(xa[rt][1], bf1, q, 0, 0, 0);
        #pragma unroll
        for (int r = 0; r < 4; r++) msg[rt][r] += q[r];
    }

    // epilogue: row = rh*64 + rt*16 + quad*4 + r, col = cq*16 + ll; scatter into agg[dst]
    #pragma unroll
    for (int rt = 0; rt < 4; rt++) {
        #pragma unroll
        for (int r = 0; r < 4; r++) {
            int el = rh * 64 + rt * 16 + quad * 4 + r;
            int eg = e0 + el;
            if (eg < NE) {
                int d = sDst[el];
                atomicAdd(&agg[d * 64 + cq * 16 + ll], msg[rt][r]);
            }
        }
    }
}

// ---- GRU via MFMA (round-8 verified; staging vectorized) ---------------------------------
__global__ __launch_bounds__(256) void k_gru(const u16* __restrict__ x1b,
                                             const float* __restrict__ agg,
                                             const float* __restrict__ Wroot,
                                             const float* __restrict__ bconv,
                                             const float* __restrict__ Wi,
                                             const float* __restrict__ Wh,
                                             const float* __restrict__ bi,
                                             const float* __restrict__ bh,
                                             const int* __restrict__ batch,
                                             float* __restrict__ pooled) {
    __shared__ __align__(16) u16 sWi[192 * 72];
    __shared__ __align__(16) u16 sWh[192 * 72];
    __shared__ __align__(16) u16 sX2[64 * 72];
    __shared__ int sBatch[64];
    const int tid = threadIdx.x;
    const int lane = tid & 63, wv = tid >> 6;
    const int ll = lane & 15, quad = lane >> 4;
    const int n0 = blockIdx.x * 64;

    for (int idx = tid; idx < 64 * 16; idx += 256) {
        int n = idx & 63, k4 = (idx >> 6) * 4;
        ushort4 a;
        a.x = f2b(Wroot[(k4 + 0) * 64 + n]);
        a.y = f2b(Wroot[(k4 + 1) * 64 + n]);
        a.z = f2b(Wroot[(k4 + 2) * 64 + n]);
        a.w = f2b(Wroot[(k4 + 3) * 64 + n]);
        *(ushort4*)&sWi[n * 72 + k4] = a;
    }
    if (tid < 64) {
        int n = n0 + tid;
        sBatch[tid] = (n < NN) ? batch[n] : -1;
    }
    __syncthreads();

    short8 ha[2];
    {
        int n = n0 + wv * 16 + ll;
        #pragma unroll
        for (int kc = 0; kc < 2; kc++) {
            if (n < NN) ha[kc] = *(const short8*)(x1b + n * 64 + kc * 32 + quad * 8);
            else        ha[kc] = (short8){0,0,0,0,0,0,0,0};
        }
    }
    f32x4 acc1[4];
    #pragma unroll
    for (int c = 0; c < 4; c++) acc1[c] = (f32x4){0.f, 0.f, 0.f, 0.f};
    #pragma unroll
    for (int kc = 0; kc < 2; kc++) {
        #pragma unroll
        for (int c = 0; c < 4; c++) {
            short8 b = *(const short8*)&sWi[(c * 16 + ll) * 72 + kc * 32 + quad * 8];
            acc1[c] = __builtin_amdgcn_mfma_f32_16x16x32_bf16(ha[kc], b, acc1[c], 0, 0, 0);
        }
    }
    #pragma unroll
    for (int c = 0; c < 4; c++) {
        int col = c * 16 + ll;
        float bcv = bconv[col];
        #pragma unroll
        for (int r = 0; r < 4; r++) {
            int row = wv * 16 + quad * 4 + r;
            int n = n0 + row;
            float v = 0.f;
            if (n < NN) v = fmaxf(acc1[c][r] + agg[n * 64 + col] + bcv, 0.f);
            sX2[row * 72 + col] = f2b(v);
        }
    }
    __syncthreads();

    for (int idx = tid; idx < 192 * 16; idx += 256) {
        int j = idx >> 4, i4 = (idx & 15) * 4;
        float4 wi4 = *(const float4*)&Wi[j * 64 + i4];
        float4 wh4 = *(const float4*)&Wh[j * 64 + i4];
        ushort4 a, b;
        a.x = f2b(wi4.x); a.y = f2b(wi4.y); a.z = f2b(wi4.z); a.w = f2b(wi4.w);
        b.x = f2b(wh4.x); b.y = f2b(wh4.y); b.z = f2b(wh4.z); b.w = f2b(wh4.w);
        *(ushort4*)&sWi[j * 72 + i4] = a;
        *(ushort4*)&sWh[j * 72 + i4] = b;
    }
    __syncthreads();

    short8 xa[2];
    #pragma unroll
    for (int kc = 0; kc < 2; kc++)
        xa[kc] = *(const short8*)&sX2[(wv * 16 + ll) * 72 + kc * 32 + quad * 8];

    f32x4 agi[12], agh[12];
    #pragma unroll
    for (int c = 0; c < 12; c++) { agi[c] = (f32x4){0.f,0.f,0.f,0.f}; agh[c] = (f32x4){0.f,0.f,0.f,0.f}; }
    #pragma unroll
    for (int kc = 0; kc < 2; kc++) {
        #pragma unroll
        for (int c = 0; c < 12; c++) {
            short8 bi8 = *(const short8*)&sWi[(c * 16 + ll) * 72 + kc * 32 + quad * 8];
            short8 bh8 = *(const short8*)&sWh[(c * 16 + ll) * 72 + kc * 32 + quad * 8];
            agi[c] = __builtin_amdgcn_mfma_f32_16x16x32_bf16(xa[kc], bi8, agi[c], 0, 0, 0);
            agh[c] = __builtin_amdgcn_mfma_f32_16x16x32_bf16(ha[kc], bh8, agh[c], 0, 0, 0);
        }
    }

    float hnv[4][4];
    #pragma unroll
    for (int c0 = 0; c0 < 4; c0++) {
        int d = c0 * 16 + ll;
        float bir = bi[d],        bhr = bh[d];
        float biz = bi[64 + d],   bhz = bh[64 + d];
        float bin = bi[128 + d],  bhn = bh[128 + d];
        #pragma unroll
        for (int r = 0; r < 4; r++) {
            int row = wv * 16 + quad * 4 + r;
            int n = n0 + row;
            float gir = agi[c0][r] + bir,     ghr = agh[c0][r] + bhr;
            float giz = agi[c0 + 4][r] + biz, ghz = agh[c0 + 4][r] + bhz;
            float gin = agi[c0 + 8][r] + bin, ghn = agh[c0 + 8][r] + bhn;
            float rg = 1.f / (1.f + __expf(-(gir + ghr)));
            float zg = 1.f / (1.f + __expf(-(giz + ghz)));
            float ng = tanhf(gin + rg * ghn);
            float hv = (n < NN) ? b2f(x1b[n * 64 + d]) : 0.f;
            hnv[c0][r] = (n < NN) ? ((1.f - zg) * ng + zg * hv) : 0.f;
        }
    }
    __syncthreads();

    float* hbuf = (float*)sWi;
    #pragma unroll
    for (int c0 = 0; c0 < 4; c0++) {
        int d = c0 * 16 + ll;
        #pragma unroll
        for (int r = 0; r < 4; r++) {
            int row = wv * 16 + quad * 4 + r;
            hbuf[row * 65 + d] = hnv[c0][r];
        }
    }
    __syncthreads();

    {
        int d = lane;
        float sum = 0.f;
        int pb = sBatch[wv * 16];
        #pragma unroll
        for (int rr = 0; rr < 16; rr++) {
            int row = wv * 16 + rr;
            int b = sBatch[row];
            float v = hbuf[row * 65 + d];
            if (b != pb) {
                if (pb >= 0) atomicAdd(&pooled[pb * 64 + d], sum);
                sum = v; pb = b;
            } else {
                sum += v;
            }
        }
        if (pb >= 0) atomicAdd(&pooled[pb * 64 + d], sum);
    }
}

// ---- heads: two 3-layer MLPs over pooled; output FLOAT32 ---------------------------------
__global__ __launch_bounds__(256) void k_heads(const float* __restrict__ pooled,
                                               const float* __restrict__ W11, const float* __restrict__ b11,
                                               const float* __restrict__ W12, const float* __restrict__ b12,
                                               const float* __restrict__ W13, const float* __restrict__ b13,
                                               const float* __restrict__ W21, const float* __restrict__ b21,
                                               const float* __restrict__ W22, const float* __restrict__ b22,
                                               const float* __restrict__ W23, const float* __restrict__ b23,
                                               float* __restrict__ out) {
    __shared__ float sV[4][64];
    __shared__ float sA[4][64];
    int tid = threadIdx.x, lane = tid & 63, wv = tid >> 6;
    int g = blockIdx.x * 4 + wv;
    if (g >= NG) return;
    float p = pooled[g * 64 + lane];
    sV[wv][lane] = p;
    float y[2];
    const float* W1s[2] = {W11, W21}; const float* b1s[2] = {b11, b21};
    const float* W2s[2] = {W12, W22}; const float* b2s[2] = {b12, b22};
    const float* W3s[2] = {W13, W23}; const float* b3s[2] = {b13, b23};
    #pragma unroll
    for (int hd = 0; hd < 2; hd++) {
        float a = b1s[hd][lane];
        #pragma unroll 8
        for (int i = 0; i < 64; i++) a += sV[wv][i] * W1s[hd][i * 64 + lane];
        a = fmaxf(a, 0.f);
        sA[wv][lane] = a;
        float a2 = b2s[hd][lane];
        #pragma unroll 8
        for (int i = 0; i < 64; i++) a2 += sA[wv][i] * W2s[hd][i * 64 + lane];
        a2 = fmaxf(a2, 0.f);
        float part = a2 * W3s[hd][lane];
        #pragma unroll
        for (int m = 32; m > 0; m >>= 1) part += __shfl_xor(part, m, 64);
        y[hd] = part + b3s[hd][0];
    }
    if (lane == 0) {
        out[g * 2 + 0] = y[0];
        out[g * 2 + 1] = y[1];
    }
}

extern "C" void kernel_launch(void* const* d_in, const int* in_sizes, int n_in,
                              void* d_out, int out_size, void* d_ws, size_t ws_size,
                              hipStream_t stream) {
    const float* x     = (const float*)d_in[0];
    const int* eidx    = (const int*)d_in[1];
    const float* ea    = (const float*)d_in[2];
    const int* batch   = (const int*)d_in[3];
    const float* W0    = (const float*)d_in[4];  const float* b0    = (const float*)d_in[5];
    const float* We1   = (const float*)d_in[6];  const float* be1   = (const float*)d_in[7];
    const float* We2   = (const float*)d_in[8];  const float* be2   = (const float*)d_in[9];
    const float* Wroot = (const float*)d_in[10]; const float* bconv = (const float*)d_in[11];
    const float* Wi    = (const float*)d_in[12]; const float* Wh    = (const float*)d_in[13];
    const float* bi    = (const float*)d_in[14]; const float* bh    = (const float*)d_in[15];
    const float* W11   = (const float*)d_in[16]; const float* b11   = (const float*)d_in[17];
    const float* W12   = (const float*)d_in[18]; const float* b12   = (const float*)d_in[19];
    const float* W13   = (const float*)d_in[20]; const float* b13   = (const float*)d_in[21];
    const float* W21   = (const float*)d_in[22]; const float* b21   = (const float*)d_in[23];
    const float* W22   = (const float*)d_in[24]; const float* b22   = (const float*)d_in[25];
    const float* W23   = (const float*)d_in[26]; const float* b23   = (const float*)d_in[27];
    float* out = (float*)d_out;

    // workspace: total 10,388,480 B
    char* ws = (char*)d_ws;
    float* agg    = (float*)(ws);                       // 6,400,000 B
    u16*   x1b    = (u16*)(ws + 6400000);               // 3,200,000 B
    u16*   Bt2    = (u16*)(ws + 9600000);               //   532,480 B
    float* pooled = (float*)(ws + 10132480);            //   256,000 B

    hipLaunchKernelGGL(k_pre, dim3(7274), dim3(256), 0, stream,
                       x, W0, b0, x1b, We2, be2, agg, pooled, Bt2);
    hipLaunchKernelGGL(k_msg, dim3(782), dim3(512), 0, stream, ea, eidx, We1, be1, x1b, Bt2, agg);
    hipLaunchKernelGGL(k_gru, dim3(391), dim3(256), 0, stream, x1b, agg, Wroot, bconv,
                       Wi, Wh, bi, bh, batch, pooled);
    hipLaunchKernelGGL(k_heads, dim3(250), dim3(256), 0, stream, pooled,
                       W11, b11, W12, b12, W13, b13, W21, b21, W22, b22, W23, b23, out);
}